// Round 3
// baseline (33948.535 us; speedup 1.0000x reference)
//
#include <hip/hip_runtime.h>
#include <stdint.h>

#define T_LEN 8192
#define HID 512
#define NTAG 12
#define START_TAG 10
#define STOP_TAG 11
#define NEGV -10000.0f

// ws layout (bytes) — ~34 MB
#define H_OFF     0u           // float [2][T][512] = 33,554,432 B
#define FEATS_OFF 33554432u    // float [T][12]     =    393,216 B
#define CNT_OFF   33947648u    // int[64]: [0]=cnt_f, [16]=cnt_b, [32]=flagF32, [33]=flag64

__device__ __forceinline__ float blo(uint32_t u) {
    union { uint32_t i; float f; } x; x.i = u << 16; return x.f;
}
__device__ __forceinline__ float bhi(uint32_t u) {
    union { uint32_t i; float f; } x; x.i = u & 0xffff0000u; return x.f;
}
__device__ __forceinline__ float b2f(uint16_t u) {
    union { uint32_t i; float f; } x; x.i = ((uint32_t)u) << 16; return x.f;
}
__device__ __forceinline__ uint32_t rne16(float f) {   // f32 -> bf16 (RNE), as uint16 in low bits
    union { float f; uint32_t i; } x; x.f = f;
    uint32_t u = x.i + 0x7FFFu + ((x.i >> 16) & 1u);
    return u >> 16;
}
__device__ __forceinline__ uint32_t pk(float f0, float f1) {  // packed bf16x2
    return rne16(f0) | (rne16(f1) << 16);
}
__device__ __forceinline__ float sigm(float x) { return 1.0f / (1.0f + expf(-x)); }

// -------- stage 0: dtype probe + counter init
__global__ __launch_bounds__(256) void k_probe(
    const uint32_t* __restrict__ embw, const int* __restrict__ sent32, int* __restrict__ cnt)
{
    __shared__ int s_bf16, s_zero;
    const int tid = threadIdx.x;
    if (tid == 0) { s_bf16 = 0; s_zero = 0; }
    __syncthreads();
    uint32_t u = embw[tid * 97 + 5];   // max idx 24,740 — in-bounds for either dtype
    float lo = b2f((uint16_t)(u & 0xFFFFu));
    float hi = b2f((uint16_t)(u >> 16));
    if (fabsf(lo) <= 8.0f && fabsf(hi) <= 8.0f) atomicAdd(&s_bf16, 1);  // NaN fails
    if (sent32[2 * tid + 1] == 0) atomicAdd(&s_zero, 1);
    __syncthreads();
    if (tid == 0) {
        cnt[32] = (s_bf16 < 224) ? 1 : 0;   // 1 => float inputs are f32
        cnt[33] = (s_zero >= 250) ? 1 : 0;  // 1 => sent is int64
    }
    if (tid < 32) cnt[tid] = 0;
}

// -------- stage 1: fused bidirectional LSTM scan (input projection folded in).
// 32 WGs: dir = bid>>4, slice w = bid&15. Each WG owns 32 h-elements.
// W_hh slice -> LDS as packed bf16 (row stride 520 hw = 1040 B, conflict-free
// lane-per-row b128); W_ih slice -> 38 packed-bf16 dwords in VGPRs;
// x_{t+1} prefetched into LDS double-buffer. Sum-barrier: counter = sum of
// per-WG completed steps; Sigma>=16s with each c_w<=max forces all c_w=s.
__global__ __launch_bounds__(512) void k_scan(
    const int* __restrict__ sent, const void* __restrict__ emb,
    const void* __restrict__ wih_f, const void* __restrict__ whh_f,
    const void* __restrict__ b_f,
    const void* __restrict__ wih_b, const void* __restrict__ whh_b,
    const void* __restrict__ b_b,
    float* __restrict__ harr, int* __restrict__ cnt)
{
    __shared__ uint16_t wlds[128 * 520];   // 133,120 B
    __shared__ float hbuf[512];
    __shared__ float partial[4][128];
    __shared__ float gbuf[128];
    __shared__ float xbuf[2][304];         // [300..303] zero pad

    const int tid = threadIdx.x;
    const int dir = blockIdx.x >> 4;
    const int w   = blockIdx.x & 15;
    const int flagF32 = cnt[32];
    const int flag64  = cnt[33];
    const void* wih = dir ? wih_b : wih_f;
    const void* whh = dir ? whh_b : whh_f;
    const void* bb  = dir ? b_b  : b_f;
    float* hd = harr + (size_t)dir * T_LEN * HID;
    int* mycnt = cnt + dir * 16;

    const int rl = tid & 127;         // local row 0..127
    const int q  = tid >> 7;          // k-quarter 0..3
    const int grow = w * 32 + (rl & 31) + 512 * (rl >> 5);   // global gate row

    // ---- stage W_hh slice into LDS (once), packed bf16 either way
    if (flagF32) {
        const float4* src = (const float4*)((const float*)whh + (size_t)grow * HID + q * 128);
        uint4* dst = (uint4*)(&wlds[rl * 520 + q * 128]);
        #pragma unroll
        for (int kk = 0; kk < 16; ++kk) {
            float4 a = src[2 * kk], b = src[2 * kk + 1];
            uint4 o;
            o.x = pk(a.x, a.y); o.y = pk(a.z, a.w);
            o.z = pk(b.x, b.y); o.w = pk(b.z, b.w);
            dst[kk] = o;
        }
    } else {
        const uint4* src = (const uint4*)((const uint16_t*)whh + (size_t)grow * HID + q * 128);
        uint4* dst = (uint4*)(&wlds[rl * 520 + q * 128]);
        #pragma unroll
        for (int kk = 0; kk < 16; ++kk) dst[kk] = src[kk];
    }
    // ---- W_ih slice into registers: elements [q*76, q*76+76) of 300, tail zero
    uint32_t wreg[38];
    if (flagF32) {
        const float* src = (const float*)wih + (size_t)grow * 300 + q * 76;
        #pragma unroll
        for (int kk = 0; kk < 38; ++kk) {
            int e = q * 76 + 2 * kk;
            float f0 = (e     < 300) ? src[2 * kk]     : 0.0f;
            float f1 = (e + 1 < 300) ? src[2 * kk + 1] : 0.0f;
            wreg[kk] = pk(f0, f1);
        }
    } else {
        const uint32_t* src = (const uint32_t*)((const uint16_t*)wih + (size_t)grow * 300 + q * 76);
        #pragma unroll
        for (int kk = 0; kk < 38; ++kk)
            wreg[kk] = (q * 76 + 2 * kk < 300) ? src[kk] : 0u;
    }
    const float bias = flagF32 ? ((const float*)bb)[grow] : b2f(((const uint16_t*)bb)[grow]);

    if (tid < 4) { xbuf[0][300 + tid] = 0.0f; xbuf[1][300 + tid] = 0.0f; }
    {   // x for step 0
        int idx0 = dir ? (T_LEN - 1) : 0;
        if (tid < 150) {
            int tok = flag64 ? sent[2 * idx0] : sent[idx0];
            if (flagF32) {
                float2 v = ((const float2*)((const float*)emb + (size_t)tok * 300))[tid];
                xbuf[0][2 * tid] = v.x; xbuf[0][2 * tid + 1] = v.y;
            } else {
                uint32_t v = ((const uint32_t*)((const uint16_t*)emb + (size_t)tok * 300))[tid];
                xbuf[0][2 * tid] = blo(v); xbuf[0][2 * tid + 1] = bhi(v);
            }
        }
    }
    __syncthreads();

    float c = 0.0f;

    for (int ts = 0; ts < T_LEN; ++ts) {
        const int idx  = dir ? (T_LEN - 1 - ts) : ts;
        const int slot = ts & 1;

        // prefetch x for step ts+1 (latency hidden under spin + matvec)
        uint32_t nxtu = 0; float2 nxtf = make_float2(0.0f, 0.0f);
        if (tid < 150) {
            int ts2  = (ts + 1 < T_LEN) ? (ts + 1) : 0;   // dummy on last step
            int idx2 = dir ? (T_LEN - 1 - ts2) : ts2;
            int tok2 = flag64 ? sent[2 * idx2] : sent[idx2];
            if (flagF32)
                nxtf = ((const float2*)((const float*)emb + (size_t)tok2 * 300))[tid];
            else
                nxtu = ((const uint32_t*)((const uint16_t*)emb + (size_t)tok2 * 300))[tid];
        }

        if (ts > 0) {
            if (tid == 0) {
                const int target = 16 * ts;
                while (__hip_atomic_load(mycnt, __ATOMIC_ACQUIRE, __HIP_MEMORY_SCOPE_AGENT) < target)
                    __builtin_amdgcn_s_sleep(2);
            }
            __syncthreads();
            const int pidx = dir ? (T_LEN - ts) : (ts - 1);
            hbuf[tid] = __hip_atomic_load(&hd[(size_t)pidx * HID + tid],
                                          __ATOMIC_RELAXED, __HIP_MEMORY_SCOPE_AGENT);
        } else {
            hbuf[tid] = 0.0f;
        }
        __syncthreads();

        {   // gate row grow: Whh[grow].h (k in q*128+[0,128)) + Wih[grow].x (q*76+[0,76))
            const uint4*  wrow = (const uint4*)(&wlds[rl * 520 + q * 128]);
            const float4* hseg = (const float4*)(&hbuf[q * 128]);
            float acc = 0.0f;
            #pragma unroll
            for (int kk = 0; kk < 16; ++kk) {
                uint4 wv = wrow[kk];
                float4 h0 = hseg[2 * kk];
                float4 h1 = hseg[2 * kk + 1];
                acc += blo(wv.x) * h0.x + bhi(wv.x) * h0.y;
                acc += blo(wv.y) * h0.z + bhi(wv.y) * h0.w;
                acc += blo(wv.z) * h1.x + bhi(wv.z) * h1.y;
                acc += blo(wv.w) * h1.z + bhi(wv.w) * h1.w;
            }
            const float2* xs2 = (const float2*)(&xbuf[slot][q * 76]);
            #pragma unroll
            for (int kk = 0; kk < 38; ++kk) {
                float2 xv = xs2[kk];
                acc += blo(wreg[kk]) * xv.x + bhi(wreg[kk]) * xv.y;
            }
            partial[q][rl] = acc;
        }
        __syncthreads();

        if (tid < 150) {   // commit prefetched x (vmcnt drains here, off critical path)
            if (flagF32) {
                xbuf[slot ^ 1][2 * tid] = nxtf.x; xbuf[slot ^ 1][2 * tid + 1] = nxtf.y;
            } else {
                xbuf[slot ^ 1][2 * tid] = blo(nxtu); xbuf[slot ^ 1][2 * tid + 1] = bhi(nxtu);
            }
        }
        if (tid < 128)
            gbuf[tid] = bias + partial[0][tid] + partial[1][tid]
                             + partial[2][tid] + partial[3][tid];
        __syncthreads();

        if (tid < 32) {
            float gi = gbuf[tid], gf = gbuf[32 + tid], gg = gbuf[64 + tid], go = gbuf[96 + tid];
            c = sigm(gf) * c + sigm(gi) * tanhf(gg);
            float h = sigm(go) * tanhf(c);
            __hip_atomic_store(&hd[(size_t)idx * HID + w * 32 + tid], h,
                               __ATOMIC_RELAXED, __HIP_MEMORY_SCOPE_AGENT);
        }
        __syncthreads();
        if (tid == 0)
            __hip_atomic_fetch_add(mycnt, 1, __ATOMIC_RELEASE, __HIP_MEMORY_SCOPE_AGENT);
    }
}

// -------- stage 2: feats[t] = log_softmax(W_proj @ [hf;hb] + b_proj)
__global__ __launch_bounds__(256) void k_feats(
    const float* __restrict__ harr, const void* __restrict__ wproj,
    const void* __restrict__ bproj, const int* __restrict__ cnt,
    float* __restrict__ feats)
{
    const int flagF32 = cnt[32];
    const int lane = threadIdx.x & 63;
    const int t = blockIdx.x * 4 + (threadIdx.x >> 6);
    const float* hf = harr;
    const float* hb = harr + (size_t)T_LEN * HID;
    float z[NTAG];
    #pragma unroll
    for (int j = 0; j < NTAG; ++j) z[j] = 0.0f;
    if (flagF32) {
        const float* wp = (const float*)wproj;
        for (int kk = lane; kk < 2 * HID; kk += 64) {
            float hv = (kk < HID) ? hf[(size_t)t * HID + kk] : hb[(size_t)t * HID + kk - HID];
            #pragma unroll
            for (int j = 0; j < NTAG; ++j) z[j] += wp[j * 2 * HID + kk] * hv;
        }
    } else {
        const uint16_t* wp = (const uint16_t*)wproj;
        for (int kk = lane; kk < 2 * HID; kk += 64) {
            float hv = (kk < HID) ? hf[(size_t)t * HID + kk] : hb[(size_t)t * HID + kk - HID];
            #pragma unroll
            for (int j = 0; j < NTAG; ++j) z[j] += b2f(wp[j * 2 * HID + kk]) * hv;
        }
    }
    #pragma unroll
    for (int j = 0; j < NTAG; ++j) {
        #pragma unroll
        for (int s = 1; s < 64; s <<= 1) z[j] += __shfl_xor(z[j], s);
        z[j] += flagF32 ? ((const float*)bproj)[j] : b2f(((const uint16_t*)bproj)[j]);
    }
    float m = z[0];
    #pragma unroll
    for (int j = 1; j < NTAG; ++j) m = fmaxf(m, z[j]);
    float se = 0.0f;
    #pragma unroll
    for (int j = 0; j < NTAG; ++j) se += expf(z[j] - m);
    float lse = m + logf(se);
    if (lane == 0) {
        #pragma unroll
        for (int j = 0; j < NTAG; ++j)
            feats[(size_t)t * NTAG + j] = z[j] - lse;
    }
}

// -------- stage 3: Viterbi forward + backtrace, single wave
__global__ __launch_bounds__(64) void k_viterbi(
    const float* __restrict__ feats, const void* __restrict__ trans,
    const int* __restrict__ cnt, float* __restrict__ out)
{
    __shared__ unsigned long long prow[T_LEN];  // 12 x 4-bit backpointers / step
    __shared__ float fbuf[448];
    const int flagF32 = cnt[32];
    const int l = threadIdx.x;
    const int jcol = (l < NTAG) ? l : 0;
    float trcol[NTAG], trstop[NTAG];
    if (flagF32) {
        const float* tr = (const float*)trans;
        #pragma unroll
        for (int i = 0; i < NTAG; ++i) { trcol[i] = tr[i * NTAG + jcol]; trstop[i] = tr[i * NTAG + STOP_TAG]; }
    } else {
        const uint16_t* tr = (const uint16_t*)trans;
        #pragma unroll
        for (int i = 0; i < NTAG; ++i) { trcol[i] = b2f(tr[i * NTAG + jcol]); trstop[i] = b2f(tr[i * NTAG + STOP_TAG]); }
    }
    float v[NTAG];
    #pragma unroll
    for (int i = 0; i < NTAG; ++i) v[i] = (i == START_TAG) ? 0.0f : NEGV;

    for (int t = 0; t < T_LEN; ++t) {
        if ((t & 31) == 0) {
            __syncthreads();
            #pragma unroll
            for (int r = 0; r < 6; ++r) {
                int g = l + r * 64;
                fbuf[g] = feats[t * NTAG + g];
            }
            __syncthreads();
        }
        float best = v[0] + trcol[0];
        int bi = 0;
        #pragma unroll
        for (int i = 1; i < NTAG; ++i) {
            float cand = v[i] + trcol[i];
            if (cand > best) { best = cand; bi = i; }   // strict >: first-index ties
        }
        float newv = best + fbuf[(t & 31) * NTAG + jcol];
        unsigned long long contrib = (l < NTAG) ? ((unsigned long long)bi << (4 * l)) : 0ull;
        #pragma unroll
        for (int s = 1; s < 16; s <<= 1) contrib |= __shfl_xor(contrib, s);
        if (l == 0) prow[t] = contrib;
        #pragma unroll
        for (int i = 0; i < NTAG; ++i) v[i] = __shfl(newv, i);
    }

    if (l == 0) {
        float best = v[0] + trstop[0];
        int bt = 0;
        #pragma unroll
        for (int i = 1; i < NTAG; ++i) {
            float cand = v[i] + trstop[i];
            if (cand > best) { best = cand; bt = i; }
        }
        out[0] = best;
        int tag = bt;
        out[T_LEN] = (float)tag;                 // tags[T-1]
        unsigned long long row = prow[T_LEN - 1];
        for (int t = T_LEN - 1; t >= 1; --t) {
            unsigned long long nxt = (t > 1) ? prow[t - 1] : 0ull;
            tag = (int)((row >> (4 * tag)) & 15ull);
            out[t] = (float)tag;                 // tags[t-1]
            row = nxt;
        }
    }
}

extern "C" void kernel_launch(void* const* d_in, const int* in_sizes, int n_in,
                              void* d_out, int out_size, void* d_ws, size_t ws_size,
                              hipStream_t stream)
{
    const int*  sent  = (const int*)d_in[0];
    const void* emb   = d_in[1];
    const void* wih_f = d_in[2];
    const void* whh_f = d_in[3];
    const void* b_f   = d_in[4];
    const void* wih_b = d_in[5];
    const void* whh_b = d_in[6];
    const void* b_b   = d_in[7];
    const void* wproj = d_in[8];
    const void* bproj = d_in[9];
    const void* trans = d_in[10];

    char* ws = (char*)d_ws;
    float* harr  = (float*)(ws + H_OFF);
    float* feats = (float*)(ws + FEATS_OFF);
    int*   cnt   = (int*)(ws + CNT_OFF);
    float* out   = (float*)d_out;

    k_probe<<<1, 256, 0, stream>>>((const uint32_t*)emb, sent, cnt);
    k_scan<<<32, 512, 0, stream>>>(sent, emb, wih_f, whh_f, b_f,
                                   wih_b, whh_b, b_b, harr, cnt);
    k_feats<<<T_LEN / 4, 256, 0, stream>>>(harr, wproj, bproj, cnt, feats);
    k_viterbi<<<1, 64, 0, stream>>>(feats, trans, cnt, out);
}